// Round 2
// baseline (654.973 us; speedup 1.0000x reference)
//
#include <hip/hip_runtime.h>
#include <hip/hip_fp16.h>

// Problem constants (fixed by the reference)
#define S_LEN 1024
#define N_B   64
#define H_DIM 1024
#define I_DIM 1024
#define M_ROWS (S_LEN * N_B)   // 65536 rows of the flattened [S*N, H] matrix

typedef __attribute__((ext_vector_type(8))) _Float16 half8;
typedef __attribute__((ext_vector_type(4))) _Float16 half4;
typedef __attribute__((ext_vector_type(4))) float    f32x4;

// ---------------------------------------------------------------------------
// async global->LDS 16B helper (wave-uniform LDS base + lane*16 layout)
// ---------------------------------------------------------------------------
__device__ __forceinline__ void gload16(const void* g, void* l) {
  __builtin_amdgcn_global_load_lds(
      (const __attribute__((address_space(1))) unsigned int*)g,
      (__attribute__((address_space(3))) unsigned int*)l, 16, 0, 0);
}

// ---------------------------------------------------------------------------
// fp32 -> fp16 convert (vectorized, grid-stride)
// ---------------------------------------------------------------------------
__global__ void cvt_f32_f16(const float* __restrict__ src,
                            _Float16* __restrict__ dst, int n4) {
  int idx = blockIdx.x * blockDim.x + threadIdx.x;
  int stride = gridDim.x * blockDim.x;
  const float4* s4 = (const float4*)src;
  half4* d4 = (half4*)dst;
  for (int i = idx; i < n4; i += stride) {
    float4 v = s4[i];
    half4 h;
    h[0] = (_Float16)v.x; h[1] = (_Float16)v.y;
    h[2] = (_Float16)v.z; h[3] = (_Float16)v.w;
    d4[i] = h;
  }
}

// ---------------------------------------------------------------------------
// u1[n][i] = hidden_d[n]·W1[i] + b1[i] + b2[i]   (fp32, tiny GEMM)
// grid: 256 blocks = (16 n-groups of 4) x (16 i-groups of 64), 256 thr
// ---------------------------------------------------------------------------
__global__ void u1_kernel(const float* __restrict__ hd,
                          const float* __restrict__ W1,
                          const float* __restrict__ b1,
                          const float* __restrict__ b2,
                          float* __restrict__ u1) {
  __shared__ float hs[4 * 1024];  // 4 rows of hidden_d
  int nb = blockIdx.x & 15;
  int ib = blockIdx.x >> 4;
  int t = threadIdx.x;
  int n0 = nb * 4;

  const float4* g4 = (const float4*)(hd + (size_t)n0 * 1024);
  float4* h4 = (float4*)hs;
#pragma unroll
  for (int r = 0; r < 4; ++r) h4[r * 256 + t] = g4[r * 256 + t];
  __syncthreads();

  int il = t >> 2, q = t & 3;      // i-local 0..63, K-quarter 0..3
  int i = ib * 64 + il;
  const float4* w4 = (const float4*)(W1 + (size_t)i * 1024 + q * 256);
  float s0 = 0.f, s1 = 0.f, s2 = 0.f, s3 = 0.f;
  for (int hh = 0; hh < 64; ++hh) {
    float4 wv = w4[hh];
    int hb = q * 256 + hh * 4;
    float4 v0 = *(const float4*)&hs[0 * 1024 + hb];
    float4 v1 = *(const float4*)&hs[1 * 1024 + hb];
    float4 v2 = *(const float4*)&hs[2 * 1024 + hb];
    float4 v3 = *(const float4*)&hs[3 * 1024 + hb];
    s0 += wv.x * v0.x + wv.y * v0.y + wv.z * v0.z + wv.w * v0.w;
    s1 += wv.x * v1.x + wv.y * v1.y + wv.z * v1.z + wv.w * v1.w;
    s2 += wv.x * v2.x + wv.y * v2.y + wv.z * v2.z + wv.w * v2.w;
    s3 += wv.x * v3.x + wv.y * v3.y + wv.z * v3.z + wv.w * v3.w;
  }
  // reduce across the 4 K-quarter lanes (q = lane&3)
  s0 += __shfl_xor(s0, 1); s0 += __shfl_xor(s0, 2);
  s1 += __shfl_xor(s1, 1); s1 += __shfl_xor(s1, 2);
  s2 += __shfl_xor(s2, 1); s2 += __shfl_xor(s2, 2);
  s3 += __shfl_xor(s3, 1); s3 += __shfl_xor(s3, 2);
  if (q == 0) {
    float bb = b1[i] + b2[i];
    u1[(size_t)(n0 + 0) * 1024 + i] = s0 + bb;
    u1[(size_t)(n0 + 1) * 1024 + i] = s1 + bb;
    u1[(size_t)(n0 + 2) * 1024 + i] = s2 + bb;
    u1[(size_t)(n0 + 3) * 1024 + i] = s3 + bb;
  }
}

// ---------------------------------------------------------------------------
// Main fused kernel:  a_ws[m] += sum_i W3[i] * tanh( A[m]·W2[i] + u1[m&63][i] )
// m97-style GEMM: 128x128 tile, BK=32, 4 waves (2x2), 16x16x32 fp16 MFMA,
// double-buffered LDS staged via global_load_lds width-16.
// grid: 4096 blocks. XCD swizzle: the 8 col-blocks (cb) sharing one A-panel
// land on ONE XCD (hw round-robins bx%8 across XCDs) -> A fetched once/panel.
//   xcd = bx&7, j = bx>>3 ; rb = xcd + 8*(j>>3), cb = j&7   (bijective)
// ---------------------------------------------------------------------------
__global__ __launch_bounds__(256) void fused_gemm_tanh(
    const _Float16* __restrict__ A,   // [65536][1024] out_e fp16
    const _Float16* __restrict__ B,   // [1024][1024]  W2 fp16 (row i = weights)
    const float* __restrict__ u1,     // [64][1024] includes b1+b2
    const float* __restrict__ W3,     // [1024]
    float* __restrict__ a_ws)         // [65536] pre-zeroed, atomic target
{
  __shared__ __align__(16) _Float16 As[2][128 * 32];  // 8KB per buf
  __shared__ __align__(16) _Float16 Bs[2][128 * 32];

  const int t = threadIdx.x;
  const int lane = t & 63;
  const int w = t >> 6;
  const int wr = w >> 1, wc = w & 1;
  const int bx = blockIdx.x;
  const int xcd = bx & 7;
  const int j = bx >> 3;
  const int rb = xcd + ((j >> 3) << 3);   // 0..511
  const int cb = j & 7;                   // 0..7
  const int m0 = rb * 128, i0 = cb * 128;

  // staging map: thread t covers row t/4 (+64 on 2nd call), 16B col (t&3)*16
  const int strow = t >> 2;
  const int stcol = (t & 3) * 8;                 // in fp16 elems
  const _Float16* gA = A + (size_t)(m0 + strow) * 1024 + stcol;
  const _Float16* gB = B + (size_t)(i0 + strow) * 1024 + stcol;
  const int ldsoff = strow * 32 + stcol;         // bytes = t*16: uniform+lane*16

  f32x4 acc[4][4] = {};

  // prologue: stage k-tile 0 into buf 0
  gload16(gA,             &As[0][ldsoff]);
  gload16(gA + 64 * 1024, &As[0][ldsoff + 64 * 32]);
  gload16(gB,             &Bs[0][ldsoff]);
  gload16(gB + 64 * 1024, &Bs[0][ldsoff + 64 * 32]);
  __syncthreads();  // compiler drains vmcnt before s_barrier

  const int fr = lane & 15;     // A-row / B-col within fragment
  const int kg = lane >> 4;     // k-group 0..3 (8 contiguous k each)
  const int aoff = (wr * 64 + fr) * 32 + kg * 8;
  const int boff = (wc * 64 + fr) * 32 + kg * 8;

  for (int kt = 0; kt < 32; ++kt) {
    const int buf = kt & 1;
    if (kt < 31) {  // prefetch next k-tile into other buffer
      const _Float16* gA2 = gA + (kt + 1) * 32;
      const _Float16* gB2 = gB + (kt + 1) * 32;
      gload16(gA2,             &As[buf ^ 1][ldsoff]);
      gload16(gA2 + 64 * 1024, &As[buf ^ 1][ldsoff + 64 * 32]);
      gload16(gB2,             &Bs[buf ^ 1][ldsoff]);
      gload16(gB2 + 64 * 1024, &Bs[buf ^ 1][ldsoff + 64 * 32]);
    }
    half8 af[4], bf[4];
#pragma unroll
    for (int mi = 0; mi < 4; ++mi)
      af[mi] = *(const half8*)&As[buf][aoff + mi * 16 * 32];
#pragma unroll
    for (int ni = 0; ni < 4; ++ni)
      bf[ni] = *(const half8*)&Bs[buf][boff + ni * 16 * 32];
#pragma unroll
    for (int mi = 0; mi < 4; ++mi)
#pragma unroll
      for (int ni = 0; ni < 4; ++ni)
        acc[mi][ni] = __builtin_amdgcn_mfma_f32_16x16x32_f16(
            af[mi], bf[ni], acc[mi][ni], 0, 0, 0);
    __syncthreads();
  }

  // Epilogue: e = acc + u1; tanh; dot with W3 over this block's i-range;
  // reduce across the 16 lanes sharing the same rows; one atomic per row.
  float w3v[4];
#pragma unroll
  for (int ni = 0; ni < 4; ++ni)
    w3v[ni] = W3[i0 + wc * 64 + ni * 16 + fr];

#pragma unroll
  for (int mi = 0; mi < 4; ++mi) {
#pragma unroll
    for (int jj = 0; jj < 4; ++jj) {
      int m = m0 + wr * 64 + mi * 16 + kg * 4 + jj;  // C/D row=(lane>>4)*4+reg
      int n = m & 63;
      const float* u1row = u1 + (size_t)n * 1024 + i0 + wc * 64;
      float s = 0.f;
#pragma unroll
      for (int ni = 0; ni < 4; ++ni) {
        float e = acc[mi][ni][jj] + u1row[ni * 16 + fr];  // C/D col=lane&15
        float th = 1.f - 2.f / (__expf(2.f * e) + 1.f);   // tanh, inf/0-safe
        s += th * w3v[ni];
      }
      s += __shfl_xor(s, 1);
      s += __shfl_xor(s, 2);
      s += __shfl_xor(s, 4);
      s += __shfl_xor(s, 8);
      if (fr == 0) atomicAdd(&a_ws[m], s);
    }
  }
}

// ---------------------------------------------------------------------------
// softmax over s for each n (b3 omitted: scalar shift is softmax-invariant)
// ---------------------------------------------------------------------------
__global__ void softmax_col(const float* __restrict__ a_ws,
                            float* __restrict__ alpha) {
  int n = blockIdx.x;
  int t = threadIdx.x;
  __shared__ float red[256];
  float v[4];
  float mx = -1e30f;
#pragma unroll
  for (int q = 0; q < 4; ++q) {
    v[q] = a_ws[(size_t)(t + q * 256) * 64 + n];
    mx = fmaxf(mx, v[q]);
  }
  red[t] = mx; __syncthreads();
  for (int off = 128; off > 0; off >>= 1) {
    if (t < off) red[t] = fmaxf(red[t], red[t + off]);
    __syncthreads();
  }
  mx = red[0];
  __syncthreads();
  float sum = 0.f;
#pragma unroll
  for (int q = 0; q < 4; ++q) { v[q] = __expf(v[q] - mx); sum += v[q]; }
  red[t] = sum; __syncthreads();
  for (int off = 128; off > 0; off >>= 1) {
    if (t < off) red[t] += red[t + off];
    __syncthreads();
  }
  float inv = 1.f / red[0];
#pragma unroll
  for (int q = 0; q < 4; ++q)
    alpha[(size_t)(t + q * 256) * 64 + n] = v[q] * inv;
}

// ---------------------------------------------------------------------------
// c[n][h] += sum_{s in chunk sc} alpha[s,n] * oe16[s,n,h]
// grid: 64 n * 16 s-chunks; thread t covers h = 4t..4t+3; atomic into c.
// ---------------------------------------------------------------------------
__global__ void weighted_sum(const _Float16* __restrict__ oe,
                             const float* __restrict__ alpha,
                             float* __restrict__ cout) {
  int n = blockIdx.x & 63;
  int sc = blockIdx.x >> 6;
  int t = threadIdx.x;
  __shared__ float al[64];
  if (t < 64) al[t] = alpha[(size_t)(sc * 64 + t) * 64 + n];
  __syncthreads();
  float a0 = 0.f, a1 = 0.f, a2 = 0.f, a3 = 0.f;
#pragma unroll 4
  for (int sl = 0; sl < 64; ++sl) {
    float a = al[sl];
    int s = sc * 64 + sl;
    half4 x = *(const half4*)(oe + (size_t)(s * 64 + n) * 1024 + t * 4);
    a0 += a * (float)x[0]; a1 += a * (float)x[1];
    a2 += a * (float)x[2]; a3 += a * (float)x[3];
  }
  float* c = cout + (size_t)n * 1024 + t * 4;
  atomicAdd(c + 0, a0);
  atomicAdd(c + 1, a1);
  atomicAdd(c + 2, a2);
  atomicAdd(c + 3, a3);
}

// ---------------------------------------------------------------------------
extern "C" void kernel_launch(void* const* d_in, const int* in_sizes, int n_in,
                              void* d_out, int out_size, void* d_ws,
                              size_t ws_size, hipStream_t stream) {
  const float* out_e    = (const float*)d_in[0];
  const float* hidden_d = (const float*)d_in[1];
  const float* W1       = (const float*)d_in[2];
  const float* b1       = (const float*)d_in[3];
  const float* W2       = (const float*)d_in[4];
  const float* b2       = (const float*)d_in[5];
  const float* W3       = (const float*)d_in[6];
  // d_in[7] = b3: scalar shift before softmax -> cancels; unused.

  // workspace layout (~134.7 MB)
  char* ws = (char*)d_ws;
  _Float16* oe16 = (_Float16*)ws;                               // 128 MB
  _Float16* w216 = (_Float16*)(ws + 134217728);                 // 2 MB
  float* u1   = (float*)(ws + 134217728 + 2097152);             // 256 KB
  float* a_ws = (float*)(ws + 134217728 + 2097152 + 262144);    // 256 KB

  float* c_out = (float*)d_out;            // [64][1024]
  float* alpha = (float*)d_out + 65536;    // [1024][64]

  hipLaunchKernelGGL(cvt_f32_f16, dim3(2048), dim3(256), 0, stream,
                     out_e, oe16, 67108864 / 4);
  hipLaunchKernelGGL(cvt_f32_f16, dim3(256), dim3(256), 0, stream,
                     W2, w216, 1048576 / 4);
  hipLaunchKernelGGL(u1_kernel, dim3(256), dim3(256), 0, stream,
                     hidden_d, W1, b1, b2, u1);
  hipMemsetAsync(a_ws, 0, 65536 * 4, stream);
  hipMemsetAsync(c_out, 0, 65536 * 4, stream);
  hipLaunchKernelGGL(fused_gemm_tanh, dim3(4096), dim3(256), 0, stream,
                     oe16, w216, u1, W3, a_ws);
  hipLaunchKernelGGL(softmax_col, dim3(64), dim3(256), 0, stream,
                     a_ws, alpha);
  hipLaunchKernelGGL(weighted_sum, dim3(1024), dim3(256), 0, stream,
                     oe16, alpha, c_out);
}